// Round 1
// baseline (245.302 us; speedup 1.0000x reference)
//
#include <hip/hip_runtime.h>
#include <hip/hip_bf16.h>

// Problem constants
#define BATCH 4096
#define NFEAT 26
#define VOCAB 10000
#define EDIM 64
#define D0 1664          // NFEAT*EDIM
#define NUMB 13
#define IN_DIM 1677      // D0 + NUMB
#define K1PAD 1696       // 53*32, zero-padded K for GEMM1
#define H1DIM 1024
#define H2DIM 512
#define H3DIM 256
#define PREDK 1920       // D0 + H3DIM
#define EPS 1e-5f

typedef __attribute__((ext_vector_type(8))) short short8;
typedef __attribute__((ext_vector_type(4))) float f32x4;

__device__ __forceinline__ void gl_lds16(const void* g, void* l) {
    __builtin_amdgcn_global_load_lds(
        (const __attribute__((address_space(1))) int*)g,
        (__attribute__((address_space(3))) int*)l, 16, 0, 0);
}

__device__ __forceinline__ void store_out(__hip_bfloat16* p, float v) { *p = __float2bfloat16(v); }
__device__ __forceinline__ void store_out(float* p, float v) { *p = v; }

// ---------------------------------------------------------------------------
// Weight convert fp32 (rows x sk) -> bf16 (rows x dk), zero pad cols sk..dk
// ---------------------------------------------------------------------------
__global__ __launch_bounds__(256) void convert_pad(const float* __restrict__ src,
                                                   __hip_bfloat16* __restrict__ dst,
                                                   int rows, int sk, int dk) {
    int i = blockIdx.x * 256 + threadIdx.x;
    if (i >= rows * dk) return;
    int r = i / dk, c = i - r * dk;
    float v = (c < sk) ? src[(size_t)r * sk + c] : 0.f;
    dst[i] = __float2bfloat16(v);
}

// ---------------------------------------------------------------------------
// K1: embedding gather + bn0 -> H0 (bf16, K1PAD cols) + cross net -> X (fp32)
// One block per batch row.
// ---------------------------------------------------------------------------
__global__ __launch_bounds__(256) void gather_cross(
    const float* __restrict__ emb, const int* __restrict__ cat,
    const float* __restrict__ numb, const float* __restrict__ bn0,
    const float* __restrict__ cw, const float* __restrict__ cb,
    float* __restrict__ X, __hip_bfloat16* __restrict__ H0) {
    __shared__ __align__(16) float x[D0];
    __shared__ int idx[NFEAT];
    __shared__ float red[4];
    const int b = blockIdx.x, tid = threadIdx.x;

    if (tid < NFEAT) idx[tid] = cat[b * NFEAT + tid];
    __syncthreads();

    // gather: 416 float4 per row (26 features x 16 float4)
    for (int j = tid; j < D0 / 4; j += 256) {
        int f = j >> 4, d4 = j & 15;
        float4 v = *(const float4*)&emb[((size_t)f * VOCAB + idx[f]) * EDIM + d4 * 4];
        *(float4*)&x[j * 4] = v;
    }
    __syncthreads();

    // h0 = bn0([x0, numb]) -> bf16, with zero pad to K1PAD
    for (int j = tid; j < K1PAD; j += 256) {
        if (j >= IN_DIM) { H0[(size_t)b * K1PAD + j] = __float2bfloat16(0.f); continue; }
        float val = (j < D0) ? x[j] : numb[b * NUMB + (j - D0)];
        float g = bn0[j], bb = bn0[IN_DIM + j], m = bn0[2 * IN_DIM + j], vv = bn0[3 * IN_DIM + j];
        float y = (val - m) * rsqrtf(vv + EPS) * g + bb;
        H0[(size_t)b * K1PAD + j] = __float2bfloat16(y);
    }

    // cross: x = x*(1 + dot(x, cw_i)) + cb_i, 3 times
    for (int it = 0; it < 3; it++) {
        __syncthreads();  // x stable (separates prior reads/writes)
        float p = 0.f;
        for (int j = tid; j < D0; j += 256) p += x[j] * cw[it * D0 + j];
        for (int o = 32; o > 0; o >>= 1) p += __shfl_down(p, o, 64);
        if ((tid & 63) == 0) red[tid >> 6] = p;
        __syncthreads();
        float s = 1.f + red[0] + red[1] + red[2] + red[3];
        float cbi = cb[it];
        for (int j = tid; j < D0; j += 256) x[j] = x[j] * s + cbi;
    }
    __syncthreads();
    for (int j = tid; j < D0 / 4; j += 256)
        *(float4*)&X[(size_t)b * D0 + j * 4] = *(const float4*)&x[j * 4];
}

// ---------------------------------------------------------------------------
// MFMA GEMM: C = A(MxK) @ W(NxK)^T, epilogue y = (c + bias - m)*g/sqrt(v+eps) + b
// A, W bf16 row-major (ld = K). 256 threads = 4 waves in 2x2 grid.
// BM = 2*MI*16, BN = 2*NI*16. K % 32 == 0, M % BM == 0, N % BN == 0.
// ---------------------------------------------------------------------------
template <int BM, int BN, int MI, int NI, typename OutT>
__global__ __launch_bounds__(256) void gemm_bn(
    const short* __restrict__ A, const short* __restrict__ Bw,
    const float* __restrict__ bias, const float* __restrict__ bn,
    OutT* __restrict__ out, int M, int N, int K) {
    __shared__ short lA[BM * 32];
    __shared__ short lB[BN * 32];
    const int tid = threadIdx.x;
    const int wave = tid >> 6, lane = tid & 63;
    const int wm = wave >> 1, wn = wave & 1;
    const int ln = lane & 15, lq = lane >> 4;
    const int m0 = blockIdx.y * BM, n0 = blockIdx.x * BN;

    f32x4 acc[MI][NI] = {};

    const int arow = tid >> 2, acol = (tid & 3) * 8;
    const size_t abase = (size_t)(m0 + arow) * K + acol;
    const size_t bbase = (size_t)(n0 + arow) * K + acol;

    for (int k0 = 0; k0 < K; k0 += 32) {
#pragma unroll
        for (int i = 0; i < BM / 64; i++)
            gl_lds16(A + abase + (size_t)i * 64 * K + k0, &lA[i * 2048 + tid * 8]);
#pragma unroll
        for (int i = 0; i < BN / 64; i++)
            gl_lds16(Bw + bbase + (size_t)i * 64 * K + k0, &lB[i * 2048 + tid * 8]);
        __syncthreads();

        short8 av[MI], bv[NI];
#pragma unroll
        for (int mi = 0; mi < MI; mi++)
            av[mi] = *(const short8*)&lA[(wm * MI * 16 + mi * 16 + ln) * 32 + lq * 8];
#pragma unroll
        for (int ni = 0; ni < NI; ni++)
            bv[ni] = *(const short8*)&lB[(wn * NI * 16 + ni * 16 + ln) * 32 + lq * 8];
#pragma unroll
        for (int mi = 0; mi < MI; mi++)
#pragma unroll
            for (int ni = 0; ni < NI; ni++)
                acc[mi][ni] = __builtin_amdgcn_mfma_f32_16x16x32_bf16(av[mi], bv[ni], acc[mi][ni], 0, 0, 0);
        __syncthreads();
    }

    // epilogue: fused bias + BN
    const float* g = bn;
    const float* bb = bn + N;
    const float* mm = bn + 2 * N;
    const float* vv = bn + 3 * N;
#pragma unroll
    for (int ni = 0; ni < NI; ni++) {
        int col = n0 + wn * NI * 16 + ni * 16 + ln;
        float sc = g[col] * rsqrtf(vv[col] + EPS);
        float sh = (bias[col] - mm[col]) * sc + bb[col];
#pragma unroll
        for (int mi = 0; mi < MI; mi++) {
            int rowb = m0 + wm * MI * 16 + mi * 16 + lq * 4;
#pragma unroll
            for (int r = 0; r < 4; r++) {
                float v = acc[mi][ni][r] * sc + sh;
                store_out(&out[(size_t)(rowb + r) * N + col], v);
            }
        }
    }
}

// ---------------------------------------------------------------------------
// K5: out[b] = sigmoid(dot(X[b], pw[0:1664]) + dot(H3[b], pw[1664:1920]) + pb)
// ---------------------------------------------------------------------------
__global__ __launch_bounds__(256) void final_pred(
    const float* __restrict__ X, const float* __restrict__ H3,
    const float* __restrict__ pw, const float* __restrict__ pb,
    float* __restrict__ out) {
    __shared__ float red[4];
    const int b = blockIdx.x, tid = threadIdx.x;
    const float4* xr = (const float4*)&X[(size_t)b * D0];
    const float4* pwx = (const float4*)pw;
    float p = 0.f;
    for (int j = tid; j < D0 / 4; j += 256) {
        float4 a = xr[j], w = pwx[j];
        p += a.x * w.x + a.y * w.y + a.z * w.z + a.w * w.w;
    }
    if (tid < H3DIM / 4) {
        const float4* hr = (const float4*)&H3[(size_t)b * H3DIM];
        const float4* pwh = (const float4*)&pw[D0];
        float4 a = hr[tid], w = pwh[tid];
        p += a.x * w.x + a.y * w.y + a.z * w.z + a.w * w.w;
    }
    for (int o = 32; o > 0; o >>= 1) p += __shfl_down(p, o, 64);
    if ((tid & 63) == 0) red[tid >> 6] = p;
    __syncthreads();
    if (tid == 0) {
        float z = red[0] + red[1] + red[2] + red[3] + pb[0];
        out[b] = 1.f / (1.f + expf(-z));
    }
}

// ---------------------------------------------------------------------------
extern "C" void kernel_launch(void* const* d_in, const int* in_sizes, int n_in,
                              void* d_out, int out_size, void* d_ws, size_t ws_size,
                              hipStream_t stream) {
    const float* numb = (const float*)d_in[0];
    const int* cat = (const int*)d_in[1];
    const float* emb = (const float*)d_in[2];
    const float* bn0 = (const float*)d_in[3];
    const float* w1 = (const float*)d_in[4];
    const float* b1 = (const float*)d_in[5];
    const float* bn1 = (const float*)d_in[6];
    const float* w2 = (const float*)d_in[7];
    const float* b2 = (const float*)d_in[8];
    const float* bn2 = (const float*)d_in[9];
    const float* w3 = (const float*)d_in[10];
    const float* b3 = (const float*)d_in[11];
    const float* bn3 = (const float*)d_in[12];
    const float* cw = (const float*)d_in[13];
    const float* cb = (const float*)d_in[14];
    const float* pw = (const float*)d_in[15];
    const float* pb = (const float*)d_in[16];
    float* out = (float*)d_out;

    char* ws = (char*)d_ws;
    // workspace layout (bytes)
    float* X = (float*)(ws + 0);                              // 4096*1664*4  = 27,262,976
    __hip_bfloat16* H0 = (__hip_bfloat16*)(ws + 27262976);    // 4096*1696*2  = 13,893,632
    __hip_bfloat16* W1b = (__hip_bfloat16*)(ws + 41156608);   // 1024*1696*2  =  3,473,408
    __hip_bfloat16* H1 = (__hip_bfloat16*)(ws + 44630016);    // 4096*1024*2  =  8,388,608
    __hip_bfloat16* W2b = (__hip_bfloat16*)(ws + 53018624);   //  512*1024*2  =  1,048,576
    __hip_bfloat16* H2 = (__hip_bfloat16*)(ws + 54067200);    // 4096*512*2   =  4,194,304
    __hip_bfloat16* W3b = (__hip_bfloat16*)(ws + 58261504);   //  256*512*2   =    262,144
    float* H3 = (float*)(ws + 58523648);                      // 4096*256*4   =  4,194,304
    // total 62,717,952 bytes

    convert_pad<<<(H1DIM * K1PAD + 255) / 256, 256, 0, stream>>>(w1, W1b, H1DIM, IN_DIM, K1PAD);
    convert_pad<<<(H2DIM * H1DIM + 255) / 256, 256, 0, stream>>>(w2, W2b, H2DIM, H1DIM, H1DIM);
    convert_pad<<<(H3DIM * H2DIM + 255) / 256, 256, 0, stream>>>(w3, W3b, H3DIM, H2DIM, H2DIM);

    gather_cross<<<BATCH, 256, 0, stream>>>(emb, cat, numb, bn0, cw, cb, X, H0);

    gemm_bn<128, 128, 4, 4, __hip_bfloat16>
        <<<dim3(H1DIM / 128, BATCH / 128), 256, 0, stream>>>(
            (const short*)H0, (const short*)W1b, b1, bn1, H1, BATCH, H1DIM, K1PAD);

    gemm_bn<64, 128, 2, 4, __hip_bfloat16>
        <<<dim3(H2DIM / 128, BATCH / 64), 256, 0, stream>>>(
            (const short*)H1, (const short*)W2b, b2, bn2, H2, BATCH, H2DIM, H1DIM);

    gemm_bn<64, 64, 2, 2, float>
        <<<dim3(H3DIM / 64, BATCH / 64), 256, 0, stream>>>(
            (const short*)H2, (const short*)W3b, b3, bn3, H3, BATCH, H3DIM, H2DIM);

    final_pred<<<BATCH, 256, 0, stream>>>(X, H3, pw, pb, out);
}

// Round 2
// 215.325 us; speedup vs baseline: 1.1392x; 1.1392x over previous
//
#include <hip/hip_runtime.h>
#include <hip/hip_bf16.h>

// Problem constants
#define BATCH 4096
#define NFEAT 26
#define VOCAB 10000
#define EDIM 64
#define D0 1664          // NFEAT*EDIM
#define NUMB 13
#define IN_DIM 1677      // D0 + NUMB
#define K1PAD 1696       // 53*32, zero-padded K for GEMM1
#define H1DIM 1024
#define H2DIM 512
#define H3DIM 256
#define EPS 1e-5f

typedef __attribute__((ext_vector_type(8))) short short8;
typedef __attribute__((ext_vector_type(4))) float f32x4;

#define LDK 40  // LDS row stride in shorts (80 B: b128-aligned, bank-uniform)

// Raw barrier: waits LDS ops only — does NOT drain vmcnt, so prefetch
// global loads stay in flight across the barrier (the m97-structure fix).
__device__ __forceinline__ void sync_lds() {
    asm volatile("s_waitcnt lgkmcnt(0)\n\ts_barrier" ::: "memory");
}

__device__ __forceinline__ void store_out(__hip_bfloat16* p, float v) { *p = __float2bfloat16(v); }
__device__ __forceinline__ void store_out(float* p, float v) { *p = v; }

// ---------------------------------------------------------------------------
// Merged weight converts fp32 -> bf16 (W1 zero-padded K 1677->1696)
// ---------------------------------------------------------------------------
__global__ __launch_bounds__(256) void convert_all(
    const float* __restrict__ w1, const float* __restrict__ w2,
    const float* __restrict__ w3,
    __hip_bfloat16* __restrict__ W1b, __hip_bfloat16* __restrict__ W2b,
    __hip_bfloat16* __restrict__ W3b) {
    int i = blockIdx.x * 256 + threadIdx.x;
    const int n1 = H1DIM * K1PAD;
    const int n2 = H2DIM * H1DIM;
    const int n3 = H3DIM * H2DIM;
    if (i < n1) {
        int r = i / K1PAD, c = i - r * K1PAD;
        W1b[i] = __float2bfloat16(c < IN_DIM ? w1[r * IN_DIM + c] : 0.f);
    } else if ((i -= n1) < n2) {
        W2b[i] = __float2bfloat16(w2[i]);
    } else if ((i -= n2) < n3) {
        W3b[i] = __float2bfloat16(w3[i]);
    }
}

// ---------------------------------------------------------------------------
// K1: embedding gather + bn0 -> H0 (bf16, K1PAD cols) + cross net
//     + Xdot[b] = dot(x_cross, pred_w[0:D0])  (X never materialized!)
// One block per batch row.
// ---------------------------------------------------------------------------
__global__ __launch_bounds__(256) void gather_cross(
    const float* __restrict__ emb, const int* __restrict__ cat,
    const float* __restrict__ numb, const float* __restrict__ bn0,
    const float* __restrict__ cw, const float* __restrict__ cb,
    const float* __restrict__ pw,
    float* __restrict__ Xdot, __hip_bfloat16* __restrict__ H0) {
    __shared__ __align__(16) float x[D0];
    __shared__ int idx[NFEAT];
    __shared__ float red[4];
    const int b = blockIdx.x, tid = threadIdx.x;

    if (tid < NFEAT) idx[tid] = cat[b * NFEAT + tid];
    __syncthreads();

    // gather: 416 float4 per row (26 features x 16 float4)
    for (int j = tid; j < D0 / 4; j += 256) {
        int f = j >> 4, d4 = j & 15;
        float4 v = *(const float4*)&emb[((size_t)f * VOCAB + idx[f]) * EDIM + d4 * 4];
        *(float4*)&x[j * 4] = v;
    }
    __syncthreads();

    // h0 = bn0([x0, numb]) -> bf16, with zero pad to K1PAD
    for (int j = tid; j < K1PAD; j += 256) {
        if (j >= IN_DIM) { H0[(size_t)b * K1PAD + j] = __float2bfloat16(0.f); continue; }
        float val = (j < D0) ? x[j] : numb[b * NUMB + (j - D0)];
        float g = bn0[j], bb = bn0[IN_DIM + j], m = bn0[2 * IN_DIM + j], vv = bn0[3 * IN_DIM + j];
        float y = (val - m) * rsqrtf(vv + EPS) * g + bb;
        H0[(size_t)b * K1PAD + j] = __float2bfloat16(y);
    }

    // cross: x = x*(1 + dot(x, cw_i)) + cb_i, 3 times
    for (int it = 0; it < 3; it++) {
        __syncthreads();
        float p = 0.f;
        for (int j = tid; j < D0; j += 256) p += x[j] * cw[it * D0 + j];
        for (int o = 32; o > 0; o >>= 1) p += __shfl_down(p, o, 64);
        if ((tid & 63) == 0) red[tid >> 6] = p;
        __syncthreads();
        float s = 1.f + red[0] + red[1] + red[2] + red[3];
        float cbi = cb[it];
        for (int j = tid; j < D0; j += 256) x[j] = x[j] * s + cbi;
    }
    __syncthreads();

    // Xdot[b] = dot(x, pw[0:D0])
    {
        float p = 0.f;
        for (int j = tid; j < D0; j += 256) p += x[j] * pw[j];
        for (int o = 32; o > 0; o >>= 1) p += __shfl_down(p, o, 64);
        if ((tid & 63) == 0) red[tid >> 6] = p;
        __syncthreads();
        if (tid == 0) Xdot[b] = red[0] + red[1] + red[2] + red[3];
    }
}

// ---------------------------------------------------------------------------
// Pipelined MFMA GEMM: C = A(MxK) @ W(NxK)^T, epilogue bias + BN.
// 256 threads = 4 waves (2x2). BM = 2*MI*16, BN = 2*NI*16.
// Depth-2 global->VGPR prefetch, ds_write into double-buffered padded LDS,
// raw lgkm-only barriers keep prefetch loads in flight across the barrier.
// ---------------------------------------------------------------------------
template <int BM, int BN, int MI, int NI, typename OutT>
__global__ __launch_bounds__(256) void gemm_bn_pipe(
    const short* __restrict__ A, const short* __restrict__ Bw,
    const float* __restrict__ bias, const float* __restrict__ bn,
    OutT* __restrict__ out, int M, int N, int K) {
    static_assert(BM == 2 * MI * 16 && BN == 2 * NI * 16, "wave grid 2x2");
    __shared__ short lA[2][BM * LDK];
    __shared__ short lB[2][BN * LDK];
    const int tid = threadIdx.x;
    const int wave = tid >> 6, lane = tid & 63;
    const int wm = wave >> 1, wn = wave & 1;
    const int ln = lane & 15, lq = lane >> 4;
    const int m0 = blockIdx.y * BM, n0 = blockIdx.x * BN;

    f32x4 acc[MI][NI] = {};

    const int arow = tid >> 2;           // 0..63
    const int acol = (tid & 3) * 8;      // shorts within 32-k
    const int KS = K / 32;

    short8 ar[BM / 64], br[BN / 64];

    auto ldg = [&](int k) {
        const int k0 = k * 32;
#pragma unroll
        for (int i = 0; i < BM / 64; i++)
            ar[i] = *(const short8*)&A[(size_t)(m0 + i * 64 + arow) * K + k0 + acol];
#pragma unroll
        for (int i = 0; i < BN / 64; i++)
            br[i] = *(const short8*)&Bw[(size_t)(n0 + i * 64 + arow) * K + k0 + acol];
    };
    auto dswr = [&](int buf) {
#pragma unroll
        for (int i = 0; i < BM / 64; i++)
            *(short8*)&lA[buf][(i * 64 + arow) * LDK + (tid & 3) * 8] = ar[i];
#pragma unroll
        for (int i = 0; i < BN / 64; i++)
            *(short8*)&lB[buf][(i * 64 + arow) * LDK + (tid & 3) * 8] = br[i];
    };

    // prologue
    ldg(0);
    dswr(0);
    if (KS > 1) ldg(1);
    sync_lds();

    for (int k = 0; k < KS; k++) {
        const int cur = k & 1;
        short8 av[MI], bv[NI];
#pragma unroll
        for (int mi = 0; mi < MI; mi++)
            av[mi] = *(const short8*)&lA[cur][(wm * MI * 16 + mi * 16 + ln) * LDK + lq * 8];
#pragma unroll
        for (int ni = 0; ni < NI; ni++)
            bv[ni] = *(const short8*)&lB[cur][(wn * NI * 16 + ni * 16 + ln) * LDK + lq * 8];
#pragma unroll
        for (int mi = 0; mi < MI; mi++)
#pragma unroll
            for (int ni = 0; ni < NI; ni++)
                acc[mi][ni] = __builtin_amdgcn_mfma_f32_16x16x32_bf16(av[mi], bv[ni], acc[mi][ni], 0, 0, 0);
        if (k + 1 < KS) {
            dswr(cur ^ 1);                 // vm-wait only for tile k+1's regs
            if (k + 2 < KS) ldg(k + 2);    // stays in flight across barrier
            sync_lds();
        }
    }

    // epilogue: fused bias + BN
    const float* g = bn;
    const float* bb = bn + N;
    const float* mm = bn + 2 * N;
    const float* vv = bn + 3 * N;
#pragma unroll
    for (int ni = 0; ni < NI; ni++) {
        int col = n0 + wn * NI * 16 + ni * 16 + ln;
        float sc = g[col] * rsqrtf(vv[col] + EPS);
        float sh = (bias[col] - mm[col]) * sc + bb[col];
#pragma unroll
        for (int mi = 0; mi < MI; mi++) {
            int rowb = m0 + wm * MI * 16 + mi * 16 + lq * 4;
#pragma unroll
            for (int r = 0; r < 4; r++) {
                float v = acc[mi][ni][r] * sc + sh;
                store_out(&out[(size_t)(rowb + r) * N + col], v);
            }
        }
    }
}

// ---------------------------------------------------------------------------
// K5: out[b] = sigmoid(Xdot[b] + dot(H3[b], pw[D0:D0+256]) + pb)
// One wave per row, 4 rows/block.
// ---------------------------------------------------------------------------
__global__ __launch_bounds__(256) void final_pred(
    const float* __restrict__ Xdot, const float* __restrict__ H3,
    const float* __restrict__ pw, const float* __restrict__ pb,
    float* __restrict__ out) {
    const int b = blockIdx.x * 4 + (threadIdx.x >> 6);
    const int lane = threadIdx.x & 63;
    float4 a = ((const float4*)&H3[(size_t)b * H3DIM])[lane];
    float4 w = ((const float4*)&pw[D0])[lane];
    float p = a.x * w.x + a.y * w.y + a.z * w.z + a.w * w.w;
    for (int o = 32; o > 0; o >>= 1) p += __shfl_down(p, o, 64);
    if (lane == 0) {
        float z = p + Xdot[b] + pb[0];
        out[b] = 1.f / (1.f + expf(-z));
    }
}

// ---------------------------------------------------------------------------
extern "C" void kernel_launch(void* const* d_in, const int* in_sizes, int n_in,
                              void* d_out, int out_size, void* d_ws, size_t ws_size,
                              hipStream_t stream) {
    const float* numb = (const float*)d_in[0];
    const int* cat = (const int*)d_in[1];
    const float* emb = (const float*)d_in[2];
    const float* bn0 = (const float*)d_in[3];
    const float* w1 = (const float*)d_in[4];
    const float* b1 = (const float*)d_in[5];
    const float* bn1 = (const float*)d_in[6];
    const float* w2 = (const float*)d_in[7];
    const float* b2 = (const float*)d_in[8];
    const float* bn2 = (const float*)d_in[9];
    const float* w3 = (const float*)d_in[10];
    const float* b3 = (const float*)d_in[11];
    const float* bn3 = (const float*)d_in[12];
    const float* cw = (const float*)d_in[13];
    const float* cb = (const float*)d_in[14];
    const float* pw = (const float*)d_in[15];
    const float* pb = (const float*)d_in[16];
    float* out = (float*)d_out;

    char* ws = (char*)d_ws;
    // workspace layout (bytes)
    __hip_bfloat16* H0  = (__hip_bfloat16*)(ws + 0);          // 4096*1696*2 = 13,893,632
    __hip_bfloat16* W1b = (__hip_bfloat16*)(ws + 13893632);   // 1024*1696*2 =  3,473,408
    __hip_bfloat16* H1  = (__hip_bfloat16*)(ws + 17367040);   // 4096*1024*2 =  8,388,608
    __hip_bfloat16* W2b = (__hip_bfloat16*)(ws + 25755648);   //  512*1024*2 =  1,048,576
    __hip_bfloat16* H2  = (__hip_bfloat16*)(ws + 26804224);   // 4096*512*2  =  4,194,304
    __hip_bfloat16* W3b = (__hip_bfloat16*)(ws + 30998528);   //  256*512*2  =    262,144
    float* H3           = (float*)(ws + 31260672);            // 4096*256*4  =  4,194,304
    float* Xdot         = (float*)(ws + 35454976);            // 4096*4      =     16,384
    // total 35,471,360 bytes

    const int ncvt = H1DIM * K1PAD + H2DIM * H1DIM + H3DIM * H2DIM;
    convert_all<<<(ncvt + 255) / 256, 256, 0, stream>>>(w1, w2, w3, W1b, W2b, W3b);

    gather_cross<<<BATCH, 256, 0, stream>>>(emb, cat, numb, bn0, cw, cb, pw, Xdot, H0);

    // GEMM1: 4096x1024 @ K=1696, BM=128 BN=64 -> 512 blocks (2/CU)
    gemm_bn_pipe<128, 64, 4, 2, __hip_bfloat16>
        <<<dim3(H1DIM / 64, BATCH / 128), 256, 0, stream>>>(
            (const short*)H0, (const short*)W1b, b1, bn1, H1, BATCH, H1DIM, K1PAD);

    // GEMM2: 4096x512 @ K=1024, BM=64 BN=64 -> 512 blocks (2/CU)
    gemm_bn_pipe<64, 64, 2, 2, __hip_bfloat16>
        <<<dim3(H2DIM / 64, BATCH / 64), 256, 0, stream>>>(
            (const short*)H1, (const short*)W2b, b2, bn2, H2, BATCH, H2DIM, H1DIM);

    // GEMM3: 4096x256 @ K=512, BM=64 BN=64 -> 256 blocks
    gemm_bn_pipe<64, 64, 2, 2, float>
        <<<dim3(H3DIM / 64, BATCH / 64), 256, 0, stream>>>(
            (const short*)H2, (const short*)W3b, b3, bn3, H3, BATCH, H3DIM, H2DIM);

    final_pred<<<BATCH / 4, 256, 0, stream>>>(Xdot, H3, pw, pb, out);
}

// Round 3
// 201.653 us; speedup vs baseline: 1.2165x; 1.0678x over previous
//
#include <hip/hip_runtime.h>
#include <hip/hip_bf16.h>

// Problem constants
#define BATCH 4096
#define NFEAT 26
#define VOCAB 10000
#define EDIM 64
#define D0 1664          // NFEAT*EDIM
#define NUMB 13
#define IN_DIM 1677      // D0 + NUMB
#define K1PAD 1696       // 53*32, zero-padded K for GEMM1
#define H1DIM 1024
#define H2DIM 512
#define H3DIM 256
#define EPS 1e-5f

typedef __attribute__((ext_vector_type(8))) short short8;
typedef __attribute__((ext_vector_type(4))) float f32x4;

#define LDK 40  // LDS row stride in shorts (80 B: b128-aligned, bank-uniform)

// Raw barrier: waits LDS ops only — does NOT drain vmcnt, so prefetch
// global loads stay in flight across the barrier.
__device__ __forceinline__ void sync_lds() {
    asm volatile("s_waitcnt lgkmcnt(0)\n\ts_barrier" ::: "memory");
}

__device__ __forceinline__ void store_out(__hip_bfloat16* p, float v) { *p = __float2bfloat16(v); }
__device__ __forceinline__ void store_out(float* p, float v) { *p = v; }

// ---------------------------------------------------------------------------
// convert_all: weight fp32->bf16 (W1 K-padded 1677->1696), bn0 scale/shift
// precompute, and cross-weight column sums (last block).
// ---------------------------------------------------------------------------
__global__ __launch_bounds__(256) void convert_all(
    const float* __restrict__ w1, const float* __restrict__ w2,
    const float* __restrict__ w3, const float* __restrict__ bn0,
    const float* __restrict__ cw, const float* __restrict__ pw,
    __hip_bfloat16* __restrict__ W1b, __hip_bfloat16* __restrict__ W2b,
    __hip_bfloat16* __restrict__ W3b,
    float* __restrict__ scale0, float* __restrict__ shift0,
    float* __restrict__ Csums) {
    const int n1 = H1DIM * K1PAD;
    const int n2 = H2DIM * H1DIM;
    const int n3 = H3DIM * H2DIM;
    const int tid = threadIdx.x;

    if (blockIdx.x == gridDim.x - 1) {
        // column sums: S0..S2 = sum(cw_i), S3 = sum(pw[0:D0])
        __shared__ float red[4][4];
        float p0 = 0.f, p1 = 0.f, p2 = 0.f, p3 = 0.f;
        for (int j = tid; j < D0; j += 256) {
            p0 += cw[j]; p1 += cw[D0 + j]; p2 += cw[2 * D0 + j]; p3 += pw[j];
        }
        for (int o = 32; o > 0; o >>= 1) {
            p0 += __shfl_down(p0, o, 64); p1 += __shfl_down(p1, o, 64);
            p2 += __shfl_down(p2, o, 64); p3 += __shfl_down(p3, o, 64);
        }
        if ((tid & 63) == 0) {
            int w = tid >> 6;
            red[w][0] = p0; red[w][1] = p1; red[w][2] = p2; red[w][3] = p3;
        }
        __syncthreads();
        if (tid < 4) Csums[tid] = red[0][tid] + red[1][tid] + red[2][tid] + red[3][tid];
        return;
    }

    int i = blockIdx.x * 256 + tid;
    if (i < n1) {
        int r = i / K1PAD, c = i - r * K1PAD;
        W1b[i] = __float2bfloat16(c < IN_DIM ? w1[r * IN_DIM + c] : 0.f);
    } else if ((i -= n1) < n2) {
        W2b[i] = __float2bfloat16(w2[i]);
    } else if ((i -= n2) < n3) {
        W3b[i] = __float2bfloat16(w3[i]);
    } else if ((i -= n3) < IN_DIM) {
        float sc = bn0[i] * rsqrtf(bn0[3 * IN_DIM + i] + EPS);
        scale0[i] = sc;
        shift0[i] = bn0[IN_DIM + i] - bn0[2 * IN_DIM + i] * sc;
    }
}

// ---------------------------------------------------------------------------
// K1: embedding gather -> H0 (bn0'd bf16, K1PAD cols) + 4 dots vs x0
// (cw_0..2 and pw[0:D0]). One block per batch row, single streaming pass.
// Cross net itself collapses to a scalar recursion done in final_pred.
// ---------------------------------------------------------------------------
__global__ __launch_bounds__(256) void gather_dots(
    const float* __restrict__ emb, const int* __restrict__ cat,
    const float* __restrict__ numb,
    const float* __restrict__ scale0, const float* __restrict__ shift0,
    const float* __restrict__ cw, const float* __restrict__ pw,
    float* __restrict__ Dots, __hip_bfloat16* __restrict__ H0) {
    __shared__ int idx[NFEAT];
    __shared__ float red[4][4];
    const int b = blockIdx.x, tid = threadIdx.x;

    if (tid < NFEAT) idx[tid] = cat[b * NFEAT + tid];
    __syncthreads();

    float d0 = 0.f, d1 = 0.f, d2 = 0.f, dp = 0.f;
    const float4* cw0 = (const float4*)cw;
    const float4* cw1 = (const float4*)(cw + D0);
    const float4* cw2 = (const float4*)(cw + 2 * D0);
    const float4* pw4 = (const float4*)pw;
    const float4* sc4 = (const float4*)scale0;
    const float4* sh4 = (const float4*)shift0;

    for (int j = tid; j < D0 / 4; j += 256) {
        int f = j >> 4, d4 = j & 15;
        float4 v = *(const float4*)&emb[((size_t)f * VOCAB + idx[f]) * EDIM + d4 * 4];
        float4 c0 = cw0[j], c1 = cw1[j], c2 = cw2[j], p4 = pw4[j];
        d0 += v.x * c0.x + v.y * c0.y + v.z * c0.z + v.w * c0.w;
        d1 += v.x * c1.x + v.y * c1.y + v.z * c1.z + v.w * c1.w;
        d2 += v.x * c2.x + v.y * c2.y + v.z * c2.z + v.w * c2.w;
        dp += v.x * p4.x + v.y * p4.y + v.z * p4.z + v.w * p4.w;
        float4 s = sc4[j], t = sh4[j];
        union { __hip_bfloat16 h[4]; short4 s4; } u;
        u.h[0] = __float2bfloat16(v.x * s.x + t.x);
        u.h[1] = __float2bfloat16(v.y * s.y + t.y);
        u.h[2] = __float2bfloat16(v.z * s.z + t.z);
        u.h[3] = __float2bfloat16(v.w * s.w + t.w);
        *(short4*)&H0[(size_t)b * K1PAD + j * 4] = u.s4;
    }

    // numb tail + zero pad (columns D0..K1PAD)
    if (tid < K1PAD - D0) {
        int jj = D0 + tid;
        float y = 0.f;
        if (jj < IN_DIM) y = numb[b * NUMB + tid] * scale0[jj] + shift0[jj];
        H0[(size_t)b * K1PAD + jj] = __float2bfloat16(y);
    }

    // reduce 4 dots
    for (int o = 32; o > 0; o >>= 1) {
        d0 += __shfl_down(d0, o, 64); d1 += __shfl_down(d1, o, 64);
        d2 += __shfl_down(d2, o, 64); dp += __shfl_down(dp, o, 64);
    }
    if ((tid & 63) == 0) {
        int w = tid >> 6;
        red[w][0] = d0; red[w][1] = d1; red[w][2] = d2; red[w][3] = dp;
    }
    __syncthreads();
    if (tid < 4) Dots[b * 4 + tid] = red[0][tid] + red[1][tid] + red[2][tid] + red[3][tid];
}

// ---------------------------------------------------------------------------
// Pipelined MFMA GEMM: C = A(MxK) @ W(NxK)^T, epilogue bias + BN.
// 256 threads = 4 waves (2x2). BM = 2*MI*16, BN = 2*NI*16.
// ---------------------------------------------------------------------------
template <int BM, int BN, int MI, int NI, typename OutT>
__global__ __launch_bounds__(256) void gemm_bn_pipe(
    const short* __restrict__ A, const short* __restrict__ Bw,
    const float* __restrict__ bias, const float* __restrict__ bn,
    OutT* __restrict__ out, int M, int N, int K) {
    static_assert(BM == 2 * MI * 16 && BN == 2 * NI * 16, "wave grid 2x2");
    __shared__ short lA[2][BM * LDK];
    __shared__ short lB[2][BN * LDK];
    const int tid = threadIdx.x;
    const int wave = tid >> 6, lane = tid & 63;
    const int wm = wave >> 1, wn = wave & 1;
    const int ln = lane & 15, lq = lane >> 4;
    const int m0 = blockIdx.y * BM, n0 = blockIdx.x * BN;

    f32x4 acc[MI][NI] = {};

    const int arow = tid >> 2;           // 0..63
    const int acol = (tid & 3) * 8;      // shorts within 32-k
    const int KS = K / 32;

    short8 ar[BM / 64], br[BN / 64];

    auto ldg = [&](int k) {
        const int k0 = k * 32;
#pragma unroll
        for (int i = 0; i < BM / 64; i++)
            ar[i] = *(const short8*)&A[(size_t)(m0 + i * 64 + arow) * K + k0 + acol];
#pragma unroll
        for (int i = 0; i < BN / 64; i++)
            br[i] = *(const short8*)&Bw[(size_t)(n0 + i * 64 + arow) * K + k0 + acol];
    };
    auto dswr = [&](int buf) {
#pragma unroll
        for (int i = 0; i < BM / 64; i++)
            *(short8*)&lA[buf][(i * 64 + arow) * LDK + (tid & 3) * 8] = ar[i];
#pragma unroll
        for (int i = 0; i < BN / 64; i++)
            *(short8*)&lB[buf][(i * 64 + arow) * LDK + (tid & 3) * 8] = br[i];
    };

    // prologue
    ldg(0);
    dswr(0);
    if (KS > 1) ldg(1);
    sync_lds();

    for (int k = 0; k < KS; k++) {
        const int cur = k & 1;
        short8 av[MI], bv[NI];
#pragma unroll
        for (int mi = 0; mi < MI; mi++)
            av[mi] = *(const short8*)&lA[cur][(wm * MI * 16 + mi * 16 + ln) * LDK + lq * 8];
#pragma unroll
        for (int ni = 0; ni < NI; ni++)
            bv[ni] = *(const short8*)&lB[cur][(wn * NI * 16 + ni * 16 + ln) * LDK + lq * 8];
#pragma unroll
        for (int mi = 0; mi < MI; mi++)
#pragma unroll
            for (int ni = 0; ni < NI; ni++)
                acc[mi][ni] = __builtin_amdgcn_mfma_f32_16x16x32_bf16(av[mi], bv[ni], acc[mi][ni], 0, 0, 0);
        if (k + 1 < KS) {
            dswr(cur ^ 1);                 // vm-wait only for tile k+1's regs
            if (k + 2 < KS) ldg(k + 2);    // stays in flight across barrier
            sync_lds();
        }
    }

    // epilogue: fused bias + BN
    const float* g = bn;
    const float* bb = bn + N;
    const float* mm = bn + 2 * N;
    const float* vv = bn + 3 * N;
#pragma unroll
    for (int ni = 0; ni < NI; ni++) {
        int col = n0 + wn * NI * 16 + ni * 16 + ln;
        float sc = g[col] * rsqrtf(vv[col] + EPS);
        float sh = (bias[col] - mm[col]) * sc + bb[col];
#pragma unroll
        for (int mi = 0; mi < MI; mi++) {
            int rowb = m0 + wm * MI * 16 + mi * 16 + lq * 4;
#pragma unroll
            for (int r = 0; r < 4; r++) {
                float v = acc[mi][ni][r] * sc + sh;
                store_out(&out[(size_t)(rowb + r) * N + col], v);
            }
        }
    }
}

// ---------------------------------------------------------------------------
// K5: cross scalar recursion + H3 dot + sigmoid. One wave per row.
// ---------------------------------------------------------------------------
__global__ __launch_bounds__(256) void final_pred(
    const float* __restrict__ Dots, const float* __restrict__ Csums,
    const float* __restrict__ cb, const float* __restrict__ H3,
    const float* __restrict__ pw, const float* __restrict__ pb,
    float* __restrict__ out) {
    const int b = blockIdx.x * 4 + (threadIdx.x >> 6);
    const int lane = threadIdx.x & 63;
    float4 a = ((const float4*)&H3[(size_t)b * H3DIM])[lane];
    float4 w = ((const float4*)&pw[D0])[lane];
    float p = a.x * w.x + a.y * w.y + a.z * w.z + a.w * w.w;
    for (int o = 32; o > 0; o >>= 1) p += __shfl_down(p, o, 64);
    if (lane == 0) {
        // cross net: x_i = P_i*x0 + Q_i*1  (scalars per row)
        float P = 1.f, Q = 0.f;
#pragma unroll
        for (int i = 0; i < 3; i++) {
            float s = 1.f + P * Dots[b * 4 + i] + Q * Csums[i];
            P = s * P;
            Q = s * Q + cb[i];
        }
        float z = P * Dots[b * 4 + 3] + Q * Csums[3] + p + pb[0];
        out[b] = 1.f / (1.f + expf(-z));
    }
}

// ---------------------------------------------------------------------------
extern "C" void kernel_launch(void* const* d_in, const int* in_sizes, int n_in,
                              void* d_out, int out_size, void* d_ws, size_t ws_size,
                              hipStream_t stream) {
    const float* numb = (const float*)d_in[0];
    const int* cat = (const int*)d_in[1];
    const float* emb = (const float*)d_in[2];
    const float* bn0 = (const float*)d_in[3];
    const float* w1 = (const float*)d_in[4];
    const float* b1 = (const float*)d_in[5];
    const float* bn1 = (const float*)d_in[6];
    const float* w2 = (const float*)d_in[7];
    const float* b2 = (const float*)d_in[8];
    const float* bn2 = (const float*)d_in[9];
    const float* w3 = (const float*)d_in[10];
    const float* b3 = (const float*)d_in[11];
    const float* bn3 = (const float*)d_in[12];
    const float* cw = (const float*)d_in[13];
    const float* cb = (const float*)d_in[14];
    const float* pw = (const float*)d_in[15];
    const float* pb = (const float*)d_in[16];
    float* out = (float*)d_out;

    char* ws = (char*)d_ws;
    // workspace layout (bytes)
    __hip_bfloat16* H0  = (__hip_bfloat16*)(ws + 0);          // 4096*1696*2 = 13,893,632
    __hip_bfloat16* W1b = (__hip_bfloat16*)(ws + 13893632);   // 1024*1696*2 =  3,473,408
    __hip_bfloat16* H1  = (__hip_bfloat16*)(ws + 17367040);   // 4096*1024*2 =  8,388,608
    __hip_bfloat16* W2b = (__hip_bfloat16*)(ws + 25755648);   //  512*1024*2 =  1,048,576
    __hip_bfloat16* H2  = (__hip_bfloat16*)(ws + 26804224);   // 4096*512*2  =  4,194,304
    __hip_bfloat16* W3b = (__hip_bfloat16*)(ws + 30998528);   //  256*512*2  =    262,144
    float* H3           = (float*)(ws + 31260672);            // 4096*256*4  =  4,194,304
    float* Dots         = (float*)(ws + 35454976);            // 4096*4*4    =     65,536
    float* Csums        = (float*)(ws + 35520512);            // 4*4 (pad 256)
    float* scale0       = (float*)(ws + 35520768);            // 1696*4
    float* shift0       = (float*)(ws + 35527552);            // 1696*4
    // total ~35,534,336 bytes

    const int ncvt = H1DIM * K1PAD + H2DIM * H1DIM + H3DIM * H2DIM + IN_DIM;
    convert_all<<<(ncvt + 255) / 256 + 1, 256, 0, stream>>>(
        w1, w2, w3, bn0, cw, pw, W1b, W2b, W3b, scale0, shift0, Csums);

    gather_dots<<<BATCH, 256, 0, stream>>>(emb, cat, numb, scale0, shift0, cw, pw, Dots, H0);

    // GEMM1: 4096x1024 @ K=1696, 128x128 (MI=NI=4) -> 256 blocks
    gemm_bn_pipe<128, 128, 4, 4, __hip_bfloat16>
        <<<dim3(H1DIM / 128, BATCH / 128), 256, 0, stream>>>(
            (const short*)H0, (const short*)W1b, b1, bn1, H1, BATCH, H1DIM, K1PAD);

    // GEMM2: 4096x512 @ K=1024, 128x64 (MI=4,NI=2) -> 256 blocks
    gemm_bn_pipe<128, 64, 4, 2, __hip_bfloat16>
        <<<dim3(H2DIM / 64, BATCH / 128), 256, 0, stream>>>(
            (const short*)H1, (const short*)W2b, b2, bn2, H2, BATCH, H2DIM, H1DIM);

    // GEMM3: 4096x256 @ K=512, 64x64 (MI=NI=2) -> 256 blocks
    gemm_bn_pipe<64, 64, 2, 2, float>
        <<<dim3(H3DIM / 64, BATCH / 64), 256, 0, stream>>>(
            (const short*)H2, (const short*)W3b, b3, bn3, H3, BATCH, H3DIM, H2DIM);

    final_pred<<<BATCH / 4, 256, 0, stream>>>(Dots, Csums, cb, H3, pw, pb, out);
}

// Round 4
// 198.764 us; speedup vs baseline: 1.2341x; 1.0145x over previous
//
#include <hip/hip_runtime.h>
#include <hip/hip_bf16.h>

// Problem constants
#define BATCH 4096
#define NFEAT 26
#define VOCAB 10000
#define EDIM 64
#define D0 1664          // NFEAT*EDIM
#define NUMB 13
#define IN_DIM 1677      // D0 + NUMB
#define K1PAD 1696       // 53*32, zero-padded K for GEMM1
#define H1DIM 1024
#define H2DIM 512
#define H3DIM 256
#define EPS 1e-5f

typedef __attribute__((ext_vector_type(8))) short short8;
typedef __attribute__((ext_vector_type(4))) float f32x4;

#define LDK 40  // LDS row stride in shorts (80 B: b128-aligned, bank-uniform)

// Raw barrier: waits LDS ops only — does NOT drain vmcnt, so prefetch
// global loads stay in flight across the barrier.
__device__ __forceinline__ void sync_lds() {
    asm volatile("s_waitcnt lgkmcnt(0)\n\ts_barrier" ::: "memory");
}

__device__ __forceinline__ void store_out(__hip_bfloat16* p, float v) { *p = __float2bfloat16(v); }
__device__ __forceinline__ void store_out(float* p, float v) { *p = v; }

// ---------------------------------------------------------------------------
// convert_all: weight fp32->bf16 (W1 K-padded 1677->1696), bn0 scale/shift
// precompute, and cross-weight column sums (last block).
// ---------------------------------------------------------------------------
__global__ __launch_bounds__(256) void convert_all(
    const float* __restrict__ w1, const float* __restrict__ w2,
    const float* __restrict__ w3, const float* __restrict__ bn0,
    const float* __restrict__ cw, const float* __restrict__ pw,
    __hip_bfloat16* __restrict__ W1b, __hip_bfloat16* __restrict__ W2b,
    __hip_bfloat16* __restrict__ W3b,
    float* __restrict__ scale0, float* __restrict__ shift0,
    float* __restrict__ Csums) {
    const int n1 = H1DIM * K1PAD;
    const int n2 = H2DIM * H1DIM;
    const int n3 = H3DIM * H2DIM;
    const int tid = threadIdx.x;

    if (blockIdx.x == gridDim.x - 1) {
        // column sums: S0..S2 = sum(cw_i), S3 = sum(pw[0:D0])
        __shared__ float red[4][4];
        float p0 = 0.f, p1 = 0.f, p2 = 0.f, p3 = 0.f;
        for (int j = tid; j < D0; j += 256) {
            p0 += cw[j]; p1 += cw[D0 + j]; p2 += cw[2 * D0 + j]; p3 += pw[j];
        }
        for (int o = 32; o > 0; o >>= 1) {
            p0 += __shfl_down(p0, o, 64); p1 += __shfl_down(p1, o, 64);
            p2 += __shfl_down(p2, o, 64); p3 += __shfl_down(p3, o, 64);
        }
        if ((tid & 63) == 0) {
            int w = tid >> 6;
            red[w][0] = p0; red[w][1] = p1; red[w][2] = p2; red[w][3] = p3;
        }
        __syncthreads();
        if (tid < 4) Csums[tid] = red[0][tid] + red[1][tid] + red[2][tid] + red[3][tid];
        return;
    }

    int i = blockIdx.x * 256 + tid;
    if (i < n1) {
        int r = i / K1PAD, c = i - r * K1PAD;
        W1b[i] = __float2bfloat16(c < IN_DIM ? w1[r * IN_DIM + c] : 0.f);
    } else if ((i -= n1) < n2) {
        W2b[i] = __float2bfloat16(w2[i]);
    } else if ((i -= n2) < n3) {
        W3b[i] = __float2bfloat16(w3[i]);
    } else if ((i -= n3) < IN_DIM) {
        float sc = bn0[i] * rsqrtf(bn0[3 * IN_DIM + i] + EPS);
        scale0[i] = sc;
        shift0[i] = bn0[IN_DIM + i] - bn0[2 * IN_DIM + i] * sc;
    }
}

// ---------------------------------------------------------------------------
// K1: embedding gather -> H0 (bn0'd bf16, K1PAD cols) + 4 dots vs x0
// (cw_0..2 and pw[0:D0]). One block per batch row, single streaming pass.
// Cross net itself collapses to a scalar recursion done in final_pred.
// ---------------------------------------------------------------------------
__global__ __launch_bounds__(256) void gather_dots(
    const float* __restrict__ emb, const int* __restrict__ cat,
    const float* __restrict__ numb,
    const float* __restrict__ scale0, const float* __restrict__ shift0,
    const float* __restrict__ cw, const float* __restrict__ pw,
    float* __restrict__ Dots, __hip_bfloat16* __restrict__ H0) {
    __shared__ int idx[NFEAT];
    __shared__ float red[4][4];
    const int b = blockIdx.x, tid = threadIdx.x;

    if (tid < NFEAT) idx[tid] = cat[b * NFEAT + tid];
    __syncthreads();

    float d0 = 0.f, d1 = 0.f, d2 = 0.f, dp = 0.f;
    const float4* cw0 = (const float4*)cw;
    const float4* cw1 = (const float4*)(cw + D0);
    const float4* cw2 = (const float4*)(cw + 2 * D0);
    const float4* pw4 = (const float4*)pw;
    const float4* sc4 = (const float4*)scale0;
    const float4* sh4 = (const float4*)shift0;

    for (int j = tid; j < D0 / 4; j += 256) {
        int f = j >> 4, d4 = j & 15;
        float4 v = *(const float4*)&emb[((size_t)f * VOCAB + idx[f]) * EDIM + d4 * 4];
        float4 c0 = cw0[j], c1 = cw1[j], c2 = cw2[j], p4 = pw4[j];
        d0 += v.x * c0.x + v.y * c0.y + v.z * c0.z + v.w * c0.w;
        d1 += v.x * c1.x + v.y * c1.y + v.z * c1.z + v.w * c1.w;
        d2 += v.x * c2.x + v.y * c2.y + v.z * c2.z + v.w * c2.w;
        dp += v.x * p4.x + v.y * p4.y + v.z * p4.z + v.w * p4.w;
        float4 s = sc4[j], t = sh4[j];
        union { __hip_bfloat16 h[4]; short4 s4; } u;
        u.h[0] = __float2bfloat16(v.x * s.x + t.x);
        u.h[1] = __float2bfloat16(v.y * s.y + t.y);
        u.h[2] = __float2bfloat16(v.z * s.z + t.z);
        u.h[3] = __float2bfloat16(v.w * s.w + t.w);
        *(short4*)&H0[(size_t)b * K1PAD + j * 4] = u.s4;
    }

    // numb tail + zero pad (columns D0..K1PAD)
    if (tid < K1PAD - D0) {
        int jj = D0 + tid;
        float y = 0.f;
        if (jj < IN_DIM) y = numb[b * NUMB + tid] * scale0[jj] + shift0[jj];
        H0[(size_t)b * K1PAD + jj] = __float2bfloat16(y);
    }

    // reduce 4 dots
    for (int o = 32; o > 0; o >>= 1) {
        d0 += __shfl_down(d0, o, 64); d1 += __shfl_down(d1, o, 64);
        d2 += __shfl_down(d2, o, 64); dp += __shfl_down(dp, o, 64);
    }
    if ((tid & 63) == 0) {
        int w = tid >> 6;
        red[w][0] = d0; red[w][1] = d1; red[w][2] = d2; red[w][3] = dp;
    }
    __syncthreads();
    if (tid < 4) Dots[b * 4 + tid] = red[0][tid] + red[1][tid] + red[2][tid] + red[3][tid];
}

// ---------------------------------------------------------------------------
// Pipelined MFMA GEMM: C = A(MxK) @ W(NxK)^T, epilogue bias + BN.
// TB threads = WR x WC waves; BM = WR*MI*16 = TB/4, BN = WC*NI*16 = TB/4
// (so each thread stages exactly one short8 of A and one of B per K-step).
// Depth-2 global->VGPR prefetch, double-buffered padded LDS, lgkm-only
// barriers keep prefetch global loads in flight across the barrier.
// ---------------------------------------------------------------------------
template <int TB, int WR, int WC, int MI, int NI, typename OutT>
__global__ __launch_bounds__(TB) void gemm_bn_pipe(
    const short* __restrict__ A, const short* __restrict__ Bw,
    const float* __restrict__ bias, const float* __restrict__ bn,
    OutT* __restrict__ out, int M, int N, int K) {
    constexpr int BM = WR * MI * 16;
    constexpr int BN = WC * NI * 16;
    static_assert(TB == WR * WC * 64, "wave grid");
    static_assert(BM * 4 == TB && BN * 4 == TB, "one short8 per thread per matrix");
    __shared__ short lA[2][BM * LDK];
    __shared__ short lB[2][BN * LDK];
    const int tid = threadIdx.x;
    const int wave = tid >> 6, lane = tid & 63;
    const int wm = wave / WC, wn = wave % WC;
    const int ln = lane & 15, lq = lane >> 4;
    const int m0 = blockIdx.y * BM, n0 = blockIdx.x * BN;

    f32x4 acc[MI][NI] = {};

    const int arow = tid >> 2;           // 0..BM-1
    const int acol = (tid & 3) * 8;      // shorts within 32-k
    const int KS = K / 32;

    short8 ar, br;

    auto ldg = [&](int k) {
        const int k0 = k * 32;
        ar = *(const short8*)&A[(size_t)(m0 + arow) * K + k0 + acol];
        br = *(const short8*)&Bw[(size_t)(n0 + arow) * K + k0 + acol];
    };
    auto dswr = [&](int buf) {
        *(short8*)&lA[buf][arow * LDK + (tid & 3) * 8] = ar;
        *(short8*)&lB[buf][arow * LDK + (tid & 3) * 8] = br;
    };

    // prologue
    ldg(0);
    dswr(0);
    if (KS > 1) ldg(1);
    sync_lds();

    for (int k = 0; k < KS; k++) {
        const int cur = k & 1;
        short8 av[MI], bv[NI];
#pragma unroll
        for (int mi = 0; mi < MI; mi++)
            av[mi] = *(const short8*)&lA[cur][(wm * MI * 16 + mi * 16 + ln) * LDK + lq * 8];
#pragma unroll
        for (int ni = 0; ni < NI; ni++)
            bv[ni] = *(const short8*)&lB[cur][(wn * NI * 16 + ni * 16 + ln) * LDK + lq * 8];
#pragma unroll
        for (int mi = 0; mi < MI; mi++)
#pragma unroll
            for (int ni = 0; ni < NI; ni++)
                acc[mi][ni] = __builtin_amdgcn_mfma_f32_16x16x32_bf16(av[mi], bv[ni], acc[mi][ni], 0, 0, 0);
        if (k + 1 < KS) {
            dswr(cur ^ 1);                 // vm-wait only for tile k+1's regs
            if (k + 2 < KS) ldg(k + 2);    // stays in flight across barrier
            sync_lds();
        }
    }

    // epilogue: fused bias + BN
    const float* g = bn;
    const float* bb = bn + N;
    const float* mm = bn + 2 * N;
    const float* vv = bn + 3 * N;
#pragma unroll
    for (int ni = 0; ni < NI; ni++) {
        int col = n0 + wn * NI * 16 + ni * 16 + ln;
        float sc = g[col] * rsqrtf(vv[col] + EPS);
        float sh = (bias[col] - mm[col]) * sc + bb[col];
#pragma unroll
        for (int mi = 0; mi < MI; mi++) {
            int rowb = m0 + wm * MI * 16 + mi * 16 + lq * 4;
#pragma unroll
            for (int r = 0; r < 4; r++) {
                float v = acc[mi][ni][r] * sc + sh;
                store_out(&out[(size_t)(rowb + r) * N + col], v);
            }
        }
    }
}

// ---------------------------------------------------------------------------
// K5: cross scalar recursion + H3 dot + sigmoid. One wave per row.
// ---------------------------------------------------------------------------
__global__ __launch_bounds__(256) void final_pred(
    const float* __restrict__ Dots, const float* __restrict__ Csums,
    const float* __restrict__ cb, const float* __restrict__ H3,
    const float* __restrict__ pw, const float* __restrict__ pb,
    float* __restrict__ out) {
    const int b = blockIdx.x * 4 + (threadIdx.x >> 6);
    const int lane = threadIdx.x & 63;
    float4 a = ((const float4*)&H3[(size_t)b * H3DIM])[lane];
    float4 w = ((const float4*)&pw[D0])[lane];
    float p = a.x * w.x + a.y * w.y + a.z * w.z + a.w * w.w;
    for (int o = 32; o > 0; o >>= 1) p += __shfl_down(p, o, 64);
    if (lane == 0) {
        // cross net: x_i = P_i*x0 + Q_i*1  (scalars per row)
        float P = 1.f, Q = 0.f;
#pragma unroll
        for (int i = 0; i < 3; i++) {
            float s = 1.f + P * Dots[b * 4 + i] + Q * Csums[i];
            P = s * P;
            Q = s * Q + cb[i];
        }
        float z = P * Dots[b * 4 + 3] + Q * Csums[3] + p + pb[0];
        out[b] = 1.f / (1.f + expf(-z));
    }
}

// ---------------------------------------------------------------------------
extern "C" void kernel_launch(void* const* d_in, const int* in_sizes, int n_in,
                              void* d_out, int out_size, void* d_ws, size_t ws_size,
                              hipStream_t stream) {
    const float* numb = (const float*)d_in[0];
    const int* cat = (const int*)d_in[1];
    const float* emb = (const float*)d_in[2];
    const float* bn0 = (const float*)d_in[3];
    const float* w1 = (const float*)d_in[4];
    const float* b1 = (const float*)d_in[5];
    const float* bn1 = (const float*)d_in[6];
    const float* w2 = (const float*)d_in[7];
    const float* b2 = (const float*)d_in[8];
    const float* bn2 = (const float*)d_in[9];
    const float* w3 = (const float*)d_in[10];
    const float* b3 = (const float*)d_in[11];
    const float* bn3 = (const float*)d_in[12];
    const float* cw = (const float*)d_in[13];
    const float* cb = (const float*)d_in[14];
    const float* pw = (const float*)d_in[15];
    const float* pb = (const float*)d_in[16];
    float* out = (float*)d_out;

    char* ws = (char*)d_ws;
    // workspace layout (bytes)
    __hip_bfloat16* H0  = (__hip_bfloat16*)(ws + 0);          // 4096*1696*2 = 13,893,632
    __hip_bfloat16* W1b = (__hip_bfloat16*)(ws + 13893632);   // 1024*1696*2 =  3,473,408
    __hip_bfloat16* H1  = (__hip_bfloat16*)(ws + 17367040);   // 4096*1024*2 =  8,388,608
    __hip_bfloat16* W2b = (__hip_bfloat16*)(ws + 25755648);   //  512*1024*2 =  1,048,576
    __hip_bfloat16* H2  = (__hip_bfloat16*)(ws + 26804224);   // 4096*512*2  =  4,194,304
    __hip_bfloat16* W3b = (__hip_bfloat16*)(ws + 30998528);   //  256*512*2  =    262,144
    float* H3           = (float*)(ws + 31260672);            // 4096*256*4  =  4,194,304
    float* Dots         = (float*)(ws + 35454976);            // 4096*4*4    =     65,536
    float* Csums        = (float*)(ws + 35520512);            // 4*4 (pad 256)
    float* scale0       = (float*)(ws + 35520768);            // 1696*4
    float* shift0       = (float*)(ws + 35527552);            // 1696*4
    // total ~35,534,336 bytes

    const int ncvt = H1DIM * K1PAD + H2DIM * H1DIM + H3DIM * H2DIM + IN_DIM;
    convert_all<<<(ncvt + 255) / 256 + 1, 256, 0, stream>>>(
        w1, w2, w3, bn0, cw, pw, W1b, W2b, W3b, scale0, shift0, Csums);

    gather_dots<<<BATCH, 256, 0, stream>>>(emb, cat, numb, scale0, shift0, cw, pw, Dots, H0);

    // GEMM1: 4096x1024 @ K=1696, 512 thr (8 waves 2x4), tile 128x128 -> 256 blocks
    gemm_bn_pipe<512, 2, 4, 4, 2, __hip_bfloat16>
        <<<dim3(H1DIM / 128, BATCH / 128), 512, 0, stream>>>(
            (const short*)H0, (const short*)W1b, b1, bn1, H1, BATCH, H1DIM, K1PAD);

    // GEMM2: 4096x512 @ K=1024, 256 thr (4 waves 2x2), tile 64x64 -> 512 blocks (2/CU)
    gemm_bn_pipe<256, 2, 2, 2, 2, __hip_bfloat16>
        <<<dim3(H2DIM / 64, BATCH / 64), 256, 0, stream>>>(
            (const short*)H1, (const short*)W2b, b2, bn2, H2, BATCH, H2DIM, H1DIM);

    // GEMM3: 4096x256 @ K=512, 256 thr, tile 64x64 -> 256 blocks
    gemm_bn_pipe<256, 2, 2, 2, 2, float>
        <<<dim3(H3DIM / 64, BATCH / 64), 256, 0, stream>>>(
            (const short*)H2, (const short*)W3b, b3, bn3, H3, BATCH, H3DIM, H2DIM);

    final_pred<<<BATCH / 4, 256, 0, stream>>>(Dots, Csums, cb, H3, pw, pb, out);
}